// Round 8
// baseline (533.537 us; speedup 1.0000x reference)
//
#include <hip/hip_runtime.h>
#include <math.h>

#define NS 150
#define LDW 152
#define NT 40
#define MS 200
#define MT 30
#define N_SWEEPS 6
#define ROUNDS (N_SWEEPS*(NT-1))
#define JITTER 0.1f
#define NTHR 512   // 8 waves: PROVEN register regime (VGPR 128 + AGPR headroom).
                   // 704 threads (R6) -> compiler caps VGPR at 84 -> scratch
                   // spills -> 6 MB HBM, +220us. Do not raise NTHR.

// ---- workspace layout (floats) ----
#define WS_AW 0                 // Acol[j][32]   : 40*32  = 1280
#define WS_RV 1280              // ra[j][256]    : 40*256 = 10240
#define WS_QV 11520             // qa[j][256]    : 40*256 = 10240 -> 21760 total

// ---- LDS union layout (bytes) ----
#define OFF_MP    0        // 47392
#define OFF_PR    47392    // 8*152*4 = 4864 -> 52256
#define OFF_INVS  52256    // 32 -> 52288
#define OFF_DVS   52288    // 600 -> 52896 (pad)
#define OFF_SCS   52896    // 1800 -> 54704 (pad)
#define OFF_TSCS  54704    // 2400 -> 57104
#define OFF_GV    58704    // 600 -> 59304
#define OFF_WTJ   59424    // 4  -> 59428
#define SMEM_BYTES 59440
// jacobi-phase overlay (inside Mp region only):
#define OFF_A2    0        // 2*40*41*4 = 13120
#define OFF_VTS   13120    // 40*44*4 = 7040 -> 20160
#define OFF_TCS   20160    // 160 -> 20320   (< OFF_PR; gv/wtj live above)

// packed upper-tri storage: row r holds cols [r&~3, 152), 16B-aligned start.
__device__ __forceinline__ int rs_off(int r) {
    int g = r >> 2, rm = r & 3;
    return LDW * r - 8 * g * (g - 1) - 4 * rm * g;
}
__device__ constexpr int rs_off_c(int r) {
    return LDW * r - 8 * (r >> 2) * ((r >> 2) - 1) - 4 * (r & 3) * (r >> 2);
}

// rotation params from the 2x2 pivot block — EXACT op sequence of the
// original jac_params (bit-identical results).
__device__ __forceinline__ void rot_cs(float app, float aqq, float apq,
                                       float& c, float& s) {
    if (apq == 0.0f) { c = 1.0f; s = 0.0f; }
    else {
        float tau = (aqq - app) / (2.0f * apq);
        float tt = ((tau >= 0.0f) ? 1.0f : -1.0f)
                   / (fabsf(tau) + sqrtf(1.0f + tau*tau));
        c = rsqrtf(1.0f + tt*tt);
        s = tt * c;
    }
}
// round-robin pair schedule: pure integer function of (item i, round rr)
__device__ __forceinline__ void sched_pq(int i, int rr, int& p, int& q) {
    p = (i == 0) ? 0 : ((i - 1 + rr) % (NT - 1)) + 1;
    q = ((NT - 2 - i + rr) % (NT - 1)) + 1;   // (NT-1-i)-1+rr
    if (p > q) { int t = p; p = q; q = t; }
}

#define ST4(K0) { \
    constexpr int b0_ = rs_off_c((K0)+0) - ((K0) & ~3); \
    constexpr int b1_ = rs_off_c((K0)+1) - ((K0) & ~3); \
    constexpr int b2_ = rs_off_c((K0)+2) - ((K0) & ~3); \
    constexpr int b3_ = rs_off_c((K0)+3) - ((K0) & ~3); \
    float uk0_ = u[(K0)+0] * Mp[b0_ + (K0)+0]; \
    qa += uk0_*uk0_;  ra += uk0_ * Mp[b0_ + 150]; \
    u[(K0)+1] -= Mp[b0_ + (K0)+1] * uk0_; \
    u[(K0)+2] -= Mp[b0_ + (K0)+2] * uk0_; \
    u[(K0)+3] -= Mp[b0_ + (K0)+3] * uk0_; \
    float uk1_ = u[(K0)+1] * Mp[b1_ + (K0)+1]; \
    qa += uk1_*uk1_;  ra += uk1_ * Mp[b1_ + 150]; \
    u[(K0)+2] -= Mp[b1_ + (K0)+2] * uk1_; \
    u[(K0)+3] -= Mp[b1_ + (K0)+3] * uk1_; \
    float uk2_ = u[(K0)+2] * Mp[b2_ + (K0)+2]; \
    qa += uk2_*uk2_;  ra += uk2_ * Mp[b2_ + 150]; \
    u[(K0)+3] -= Mp[b2_ + (K0)+3] * uk2_; \
    float uk3_ = u[(K0)+3] * Mp[b3_ + (K0)+3]; \
    qa += uk3_*uk3_;  ra += uk3_ * Mp[b3_ + 150]; \
    _Pragma("unroll") \
    for (int t_ = (K0)+4; t_ < NS; t_ += 4) { \
        float4 w0_ = *(const float4*)&Mp[b0_ + t_]; \
        float4 w1_ = *(const float4*)&Mp[b1_ + t_]; \
        float4 w2_ = *(const float4*)&Mp[b2_ + t_]; \
        float4 w3_ = *(const float4*)&Mp[b3_ + t_]; \
        u[t_+0] -= w0_.x*uk0_ + w1_.x*uk1_ + w2_.x*uk2_ + w3_.x*uk3_; \
        u[t_+1] -= w0_.y*uk0_ + w1_.y*uk1_ + w2_.y*uk2_ + w3_.y*uk3_; \
        u[t_+2] -= w0_.z*uk0_ + w1_.z*uk1_ + w2_.z*uk2_ + w3_.z*uk3_; \
        u[t_+3] -= w0_.w*uk0_ + w1_.w*uk1_ + w2_.w*uk2_ + w3_.w*uk3_; \
    } \
}

#define UI(K) { \
    float d0_ = tx - scs[(K)*3+0]; \
    float d1_ = ty - scs[(K)*3+1]; \
    float d2_ = tz - scs[(K)*3+2]; \
    u[(K)] = expf(-((d0_*d0_ + d1_*d1_)*ill2 + d2_*d2_*ile2)); }
#define UI10(K) UI((K)+0) UI((K)+1) UI((K)+2) UI((K)+3) UI((K)+4) \
                UI((K)+5) UI((K)+6) UI((K)+7) UI((K)+8) UI((K)+9)

// ONE main kernel, 40 blocks x 512 threads.
// Jacobi round restructured (R7 post-mortem: shfl distribution was SLOWER
// than prm-LDS — distribution itself is the bottleneck). Now ZERO
// cross-lane traffic: the pair indices (p,q) are a pure integer function
// of (item, round), so every thread computes them locally and computes its
// needed (c,s) chains REDUNDANTLY (A-threads: 2 chains; V-threads: 1).
// All ~10 LDS loads per thread have integer-derived addresses -> issued
// concurrently at round start -> ONE LDS latency instead of three
// serialized (param-read -> distribute -> data-read). VALUBusy was 6%:
// redundant param VALU is free. Op sequences identical -> bit-identical out.
__global__ void __launch_bounds__(NTHR, 2) gp_block(
        const float* __restrict__ sc,  const float* __restrict__ tc,
        const float* __restrict__ st,  const float* __restrict__ tsc,
        const float* __restrict__ ttc,
        const float* __restrict__ lll, const float* __restrict__ lle,
        const float* __restrict__ llt, const float* __restrict__ lnv,
        float* __restrict__ ws) {
    __shared__ __align__(16) char smem[SMEM_BYTES];
    int j = blockIdx.x, tid = threadIdx.x;

    auto A2   = (float (*)[NT][NT+1])(smem + OFF_A2);
    auto Vts  = (float (*)[44])(smem + OFF_VTS);
    float* tcs  = (float*)(smem + OFF_TCS);
    float* gv   = (float*)(smem + OFF_GV);
    float* wtjs = (float*)(smem + OFF_WTJ);
    float* scs  = (float*)(smem + OFF_SCS);
    float* tscs = (float*)(smem + OFF_TSCS);

    float ilt2 = expf(-2.0f * llt[0]);
    if (tid < NT) tcs[tid] = tc[tid];
    for (int t = tid; t < NS*3; t += NTHR) scs[t] = sc[t];
    for (int t = tid; t < MS*3; t += NTHR) tscs[t] = tsc[t];
    __syncthreads();
    for (int idx = tid; idx < NT*NT; idx += NTHR) {
        int i = idx / NT, jj = idx - i*NT;
        float dt = tcs[i] - tcs[jj];
        float v = expf(-dt*dt*ilt2);
        if (i == jj) v += JITTER;
        A2[0][i][jj] = v;
    }
    for (int idx = tid; idx < NT*44; idx += NTHR) {
        int jr = idx / 44, k = idx - jr*44;
        Vts[jr][k] = (jr == k) ? 1.0f : 0.0f;
    }
    __syncthreads();

    // static item assignment (round-invariant)
    const int ta = (tid < 400) ? tid : 0;            // A-item index
    const int bi = ta / 20, bj = ta - bi*20;
    const int tv = (tid >= 400 && tid < 500) ? (tid - 400) : 0;  // V-item
    const int pr = tv / 5, ch = (tv - pr*5) << 3;    // pair, col*8
    for (int rd = 0; rd < ROUNDS; ++rd) {
        int cur = rd & 1, nxt = cur ^ 1;
        int rr = rd % (NT - 1);
        if (tid < 400) {
            // pair indices: pure integer math, available at round start
            int pi, qi, pj, qj;
            sched_pq(bi, rr, pi, qi);
            sched_pq(bj, rr, pj, qj);
            // issue ALL loads up front (param + trailing data, one latency)
            float app_i = A2[cur][pi][pi], aqq_i = A2[cur][qi][qi];
            float apq_i = A2[cur][pi][qi];
            float app_j = A2[cur][pj][pj], aqq_j = A2[cur][qj][qj];
            float apq_j = A2[cur][pj][qj];
            float a00 = A2[cur][pi][pj], a01 = A2[cur][pi][qj];
            float a10 = A2[cur][qi][pj], a11 = A2[cur][qi][qj];
            // redundant param chains (VALU, ~free at 6% VALUBusy)
            float ci, si, cj, sj;
            rot_cs(app_i, aqq_i, apq_i, ci, si);
            rot_cs(app_j, aqq_j, apq_j, cj, sj);
            float b00 = ci*a00 - si*a10, b01 = ci*a01 - si*a11;
            float b10 = si*a00 + ci*a10, b11 = si*a01 + ci*a11;
            A2[nxt][pi][pj] = cj*b00 - sj*b01; A2[nxt][pi][qj] = sj*b00 + cj*b01;
            A2[nxt][qi][pj] = cj*b10 - sj*b11; A2[nxt][qi][qj] = sj*b10 + cj*b11;
        } else if (tid < 500) {
            int pv, qv;
            sched_pq(pr, rr, pv, qv);
            float app = A2[cur][pv][pv], aqq = A2[cur][qv][qv];
            float apq = A2[cur][pv][qv];
            float4 vp0 = *(float4*)&Vts[pv][ch];
            float4 vp1 = *(float4*)&Vts[pv][ch+4];
            float4 vq0 = *(float4*)&Vts[qv][ch];
            float4 vq1 = *(float4*)&Vts[qv][ch+4];
            float cv, sv;
            rot_cs(app, aqq, apq, cv, sv);
            float4 np0, np1, nq0, nq1;
            np0.x = cv*vp0.x - sv*vq0.x; nq0.x = sv*vp0.x + cv*vq0.x;
            np0.y = cv*vp0.y - sv*vq0.y; nq0.y = sv*vp0.y + cv*vq0.y;
            np0.z = cv*vp0.z - sv*vq0.z; nq0.z = sv*vp0.z + cv*vq0.z;
            np0.w = cv*vp0.w - sv*vq0.w; nq0.w = sv*vp0.w + cv*vq0.w;
            np1.x = cv*vp1.x - sv*vq1.x; nq1.x = sv*vp1.x + cv*vq1.x;
            np1.y = cv*vp1.y - sv*vq1.y; nq1.y = sv*vp1.y + cv*vq1.y;
            np1.z = cv*vp1.z - sv*vq1.z; nq1.z = sv*vp1.z + cv*vq1.z;
            np1.w = cv*vp1.w - sv*vq1.w; nq1.w = sv*vp1.w + cv*vq1.w;
            *(float4*)&Vts[pv][ch]   = np0;
            *(float4*)&Vts[pv][ch+4] = np1;
            *(float4*)&Vts[qv][ch]   = nq0;
            *(float4*)&Vts[qv][ch+4] = nq1;
        }
        __syncthreads();
    }
    const int fin = ROUNDS & 1;
    if (tid == 0) wtjs[0] = A2[fin][j][j];
    for (int s = tid; s < NS; s += NTHR) {
        const float4* va = (const float4*)&Vts[j][0];
        const float4* sa = (const float4*)&st[s*NT];
        float acc = 0.0f;
        #pragma unroll
        for (int c4 = 0; c4 < NT/4; ++c4) {
            float4 a = va[c4], b = sa[c4];
            acc += a.x*b.x + a.y*b.y + a.z*b.z + a.w*b.w;
        }
        gv[s] = acc;
    }
    if (tid < MT) {
        float ttv = ttc[tid];
        float acc = 0.0f;
        for (int t = 0; t < NT; ++t) {
            float dt = ttv - tcs[t];
            acc += expf(-dt*dt*ilt2) * Vts[j][t];
        }
        ws[WS_AW + j*32 + tid] = acc;
    }
    __syncthreads();

    // ---------- phase 2: build + rank-8 factor + scale + trsm ----------
    float* Mp   = (float*)(smem + OFF_MP);
    auto   Pr   = (float (*)[LDW])(smem + OFF_PR);
    float* invs = (float*)(smem + OFF_INVS);
    float* dvs  = (float*)(smem + OFF_DVS);
    float wtj = wtjs[0];
    float nv = expf(lnv[0]);
    float ill2 = expf(-2.0f * lll[0]);
    float ile2 = expf(-2.0f * lle[0]);
    for (int idx = tid; idx < NS*LDW; idx += NTHR) {
        int r = idx / LDW, c = idx - r*LDW;
        int rbase = r & ~3;
        if (c < rbase) continue;
        float v;
        if (c < NS) {
            float d0 = scs[r*3+0] - scs[c*3+0];
            float d1 = scs[r*3+1] - scs[c*3+1];
            float d2 = scs[r*3+2] - scs[c*3+2];
            v = wtj * expf(-((d0*d0 + d1*d1)*ill2 + d2*d2*ile2));
            if (c == r) v += wtj * JITTER + nv;   // spatial jitter rides wtj
        } else if (c == NS) {
            v = gv[r];
        } else {
            v = 0.0f;
        }
        Mp[rs_off(r) + c - rbase] = v;
    }
    __syncthreads();
    for (int k0 = 0; k0 < NS - 1; k0 += 8) {
        int P = NS - k0; if (P > 8) P = 8;
        int W4 = (LDW - k0) >> 2;
        // phase A (single wave): redundant 8x8 elimination + chunk pre-elim -> Pr
        if (tid < W4) {
            int off[8];
            #pragma unroll
            for (int i = 0; i < 8; ++i)
                off[i] = (i < P) ? (rs_off(k0 + i) - ((i >= 4) ? 4 : 0)) : 0;
            float Bm[8][8];
            #pragma unroll
            for (int i = 0; i < 8; ++i) {
                #pragma unroll
                for (int c = 0; c < 8; ++c)
                    Bm[i][c] = (i < P && c >= i) ? Mp[off[i] + c]
                                                 : ((c == i) ? 1.0f : 0.0f);
            }
            float Lf[8][8]; float iv[8];
            #pragma unroll
            for (int k = 0; k < 8; ++k) {
                iv[k] = 1.0f / Bm[k][k];
                #pragma unroll
                for (int i = k + 1; i < 8; ++i) {
                    float l = Bm[k][i] * iv[k];
                    Lf[i][k] = l;
                    #pragma unroll
                    for (int c = i; c < 8; ++c) Bm[i][c] -= l * Bm[k][c];
                }
            }
            if (tid == 0) {
                #pragma unroll
                for (int i = 0; i < 8; ++i) invs[i] = iv[i];
            }
            int C = tid << 2;
            float4 m[8];
            #pragma unroll
            for (int i = 0; i < 8; ++i) {
                bool ok = (i < P) && (i < 4 || C >= 4);
                m[i] = ok ? *(float4*)&Mp[off[i] + C] : make_float4(0,0,0,0);
            }
            #pragma unroll
            for (int i = 1; i < 8; ++i) {
                #pragma unroll
                for (int k = 0; k < i; ++k) {
                    float l = Lf[i][k];
                    m[i].x -= l*m[k].x; m[i].y -= l*m[k].y;
                    m[i].z -= l*m[k].z; m[i].w -= l*m[k].w;
                }
            }
            #pragma unroll
            for (int i = 0; i < 8; ++i) *(float4*)&Pr[i][C] = m[i];
        }
        __syncthreads();
        // phase B: rank-8 trailing update, thread-per-row, contiguous f4 sweep
        for (int r = k0 + 1 + tid; r < NS; r += NTHR) {
            int rc = r - k0;
            float f[8];
            #pragma unroll
            for (int i = 0; i < 8; ++i)
                f[i] = (rc > i && i < P) ? Pr[i][rc] * invs[i] : 0.0f;
            int rbase = r & ~3;
            int ro = rs_off(r) - rbase;
            for (int C = rbase; C < LDW; C += 4) {
                int pc = C - k0;
                float4 v = *(float4*)&Mp[ro + C];
                #pragma unroll
                for (int i = 0; i < 8; ++i) {
                    float4 p = *(float4*)&Pr[i][pc];
                    v.x -= f[i]*p.x; v.y -= f[i]*p.y;
                    v.z -= f[i]*p.z; v.w -= f[i]*p.w;
                }
                *(float4*)&Mp[ro + C] = v;
            }
        }
        __syncthreads();
    }
    // scale in place: diag slot = 1/d, cols>r (incl. RHS col 150 -> y) *= 1/d
    for (int r = tid; r < NS; r += NTHR)
        dvs[r] = rsqrtf(Mp[rs_off(r) + r - (r & ~3)]);
    __syncthreads();
    for (int idx = tid; idx < NS*LDW; idx += NTHR) {
        int r = idx / LDW, c = idx - r*LDW;
        int rbase = r & ~3;
        if (c < rbase) continue;
        int t = rs_off(r) + c - rbase;
        float dvr = dvs[r];
        if (c == r) Mp[t] = dvr;
        else if (c > r) Mp[t] *= dvr;
    }
    __syncthreads();
    // fused trsm: thread-per-test-column, u[] fully static -> register/AGPR
    if (tid < MS) {
        float tx = tscs[tid*3+0], ty = tscs[tid*3+1], tz = tscs[tid*3+2];
        float u[152];
        UI10(0)  UI10(10) UI10(20) UI10(30) UI10(40)
        UI10(50) UI10(60) UI10(70) UI10(80) UI10(90)
        UI10(100) UI10(110) UI10(120) UI10(130) UI10(140)
        u[150] = 0.0f; u[151] = 0.0f;
        float qa = 0.0f, ra = 0.0f;
        ST4(0)   ST4(4)   ST4(8)   ST4(12)  ST4(16)  ST4(20)  ST4(24)
        ST4(28)  ST4(32)  ST4(36)  ST4(40)  ST4(44)  ST4(48)  ST4(52)
        ST4(56)  ST4(60)  ST4(64)  ST4(68)  ST4(72)  ST4(76)  ST4(80)
        ST4(84)  ST4(88)  ST4(92)  ST4(96)  ST4(100) ST4(104) ST4(108)
        ST4(112) ST4(116) ST4(120) ST4(124) ST4(128) ST4(132) ST4(136)
        ST4(140) ST4(144)
        {   // tail: k = 148, 149
            constexpr int b8_ = rs_off_c(148) - 148;
            constexpr int b9_ = rs_off_c(149) - 148;
            float uk8_ = u[148] * Mp[b8_ + 148];
            qa += uk8_*uk8_;  ra += uk8_ * Mp[b8_ + 150];
            u[149] -= Mp[b8_ + 149] * uk8_;
            float uk9_ = u[149] * Mp[b9_ + 149];
            qa += uk9_*uk9_;  ra += uk9_ * Mp[b9_ + 150];
        }
        ws[WS_RV + j*256 + tid] = ra;
        ws[WS_QV + j*256 + tid] = qa;
    }
}

// ---------- reduction kernel: out = rank-40 combine of workspace partials ----------
__global__ void __launch_bounds__(256) gp_reduce(
        const float* __restrict__ ws, const float* __restrict__ lsv,
        float* __restrict__ out) {
    int idx = blockIdx.x * 256 + threadIdx.x;
    if (idx >= MS*MT) return;
    int is = idx / MT, it = idx - is*MT;
    float p = 0.0f, q = 0.0f;
    #pragma unroll
    for (int jj = 0; jj < NT; ++jj) {
        float a = ws[WS_AW + jj*32 + it];
        p += a * ws[WS_RV + jj*256 + is];
        q += a * a * ws[WS_QV + jj*256 + is];
    }
    out[idx] = p;
    out[MS*MT + idx] = expf(lsv[0]) - q;
}

extern "C" void kernel_launch(void* const* d_in, const int* in_sizes, int n_in,
                              void* d_out, int out_size, void* d_ws, size_t ws_size,
                              hipStream_t stream) {
    const float* sc  = (const float*)d_in[0];   // 150x3
    const float* tc  = (const float*)d_in[1];   // 40x1
    const float* st  = (const float*)d_in[2];   // 150x40
    const float* tsc = (const float*)d_in[3];   // 200x3
    const float* ttc = (const float*)d_in[4];   // 30x1
    const float* lll = (const float*)d_in[5];
    const float* lle = (const float*)d_in[6];
    const float* llt = (const float*)d_in[7];
    const float* lnv = (const float*)d_in[8];
    const float* lsv = (const float*)d_in[9];
    float* out = (float*)d_out;
    float* ws  = (float*)d_ws;

    hipLaunchKernelGGL(gp_block, dim3(NT), dim3(NTHR), 0, stream,
                       sc, tc, st, tsc, ttc, lll, lle, llt, lnv, ws);
    hipLaunchKernelGGL(gp_reduce, dim3((MS*MT + 255)/256), dim3(256), 0, stream,
                       ws, lsv, out);
}

// Round 9
// 460.971 us; speedup vs baseline: 1.1574x; 1.1574x over previous
//
#include <hip/hip_runtime.h>
#include <math.h>

#define NS 150
#define LDW 152
#define NT 40
#define MS 200
#define MT 30
#define N_SWEEPS 6
#define ROUNDS (N_SWEEPS*(NT-1))
#define JITTER 0.1f
#define NTHR 512   // 8 waves: PROVEN register regime (VGPR 128 + AGPR headroom).
                   // 704 threads (R6) -> compiler caps VGPR at 84 -> scratch
                   // spills -> 6 MB HBM, +220us. Do not raise NTHR.

// ---- workspace layout (floats) ----
#define WS_AW 0                 // Acol[j][32]   : 40*32  = 1280
#define WS_RV 1280              // ra[j][256]    : 40*256 = 10240
#define WS_QV 11520             // qa[j][256]    : 40*256 = 10240 -> 21760 total

// ---- LDS union layout (bytes) ----
#define OFF_MP    0        // 47392
#define OFF_PR    47392    // 8*152*4 = 4864 -> 52256
#define OFF_INVS  52256    // 32 -> 52288
#define OFF_DVS   52288    // 600 -> 52896 (pad)
#define OFF_SCS   52896    // 1800 -> 54704 (pad)
#define OFF_TSCS  54704    // 2400 -> 57104
#define OFF_GV    58704    // 600 -> 59304
#define OFF_WTJ   59424    // 4  -> 59428
#define SMEM_BYTES 59440
// jacobi-phase overlay (inside Mp region only):
#define OFF_A2    0        // 2*40*41*4 = 13120
#define OFF_VTS   13120    // 40*44*4 = 7040 -> 20160
#define OFF_PRM   20160    // 8*20*8 = 1280 -> 21440 (float2 now)
#define OFF_TCS   22720    // 160 -> 22880   (< OFF_PR; gv/wtj live above)

// packed upper-tri storage: row r holds cols [r&~3, 152), 16B-aligned start.
__device__ __forceinline__ int rs_off(int r) {
    int g = r >> 2, rm = r & 3;
    return LDW * r - 8 * g * (g - 1) - 4 * rm * g;
}
__device__ constexpr int rs_off_c(int r) {
    return LDW * r - 8 * (r >> 2) * ((r >> 2) - 1) - 4 * (r & 3) * (r >> 2);
}

// rotation params from the 2x2 pivot block — EXACT op sequence of the
// original jac_params (bit-identical results).
__device__ __forceinline__ void rot_cs(float app, float aqq, float apq,
                                       float& c, float& s) {
    if (apq == 0.0f) { c = 1.0f; s = 0.0f; }
    else {
        float tau = (aqq - app) / (2.0f * apq);
        float tt = ((tau >= 0.0f) ? 1.0f : -1.0f)
                   / (fabsf(tau) + sqrtf(1.0f + tau*tau));
        c = rsqrtf(1.0f + tt*tt);
        s = tt * c;
    }
}
// round-robin pair schedule: pure integer function of (item i, round rr).
// Proven bit-exact vs jac_params' indices (R8 passed with same absmax).
__device__ __forceinline__ void sched_pq(int i, int rr, int& p, int& q) {
    p = (i == 0) ? 0 : ((i - 1 + rr) % (NT - 1)) + 1;
    q = ((NT - 2 - i + rr) % (NT - 1)) + 1;   // (NT-1-i)-1+rr
    if (p > q) { int t = p; p = q; q = t; }
}

#define ST4(K0) { \
    constexpr int b0_ = rs_off_c((K0)+0) - ((K0) & ~3); \
    constexpr int b1_ = rs_off_c((K0)+1) - ((K0) & ~3); \
    constexpr int b2_ = rs_off_c((K0)+2) - ((K0) & ~3); \
    constexpr int b3_ = rs_off_c((K0)+3) - ((K0) & ~3); \
    float uk0_ = u[(K0)+0] * Mp[b0_ + (K0)+0]; \
    qa += uk0_*uk0_;  ra += uk0_ * Mp[b0_ + 150]; \
    u[(K0)+1] -= Mp[b0_ + (K0)+1] * uk0_; \
    u[(K0)+2] -= Mp[b0_ + (K0)+2] * uk0_; \
    u[(K0)+3] -= Mp[b0_ + (K0)+3] * uk0_; \
    float uk1_ = u[(K0)+1] * Mp[b1_ + (K0)+1]; \
    qa += uk1_*uk1_;  ra += uk1_ * Mp[b1_ + 150]; \
    u[(K0)+2] -= Mp[b1_ + (K0)+2] * uk1_; \
    u[(K0)+3] -= Mp[b1_ + (K0)+3] * uk1_; \
    float uk2_ = u[(K0)+2] * Mp[b2_ + (K0)+2]; \
    qa += uk2_*uk2_;  ra += uk2_ * Mp[b2_ + 150]; \
    u[(K0)+3] -= Mp[b2_ + (K0)+3] * uk2_; \
    float uk3_ = u[(K0)+3] * Mp[b3_ + (K0)+3]; \
    qa += uk3_*uk3_;  ra += uk3_ * Mp[b3_ + 150]; \
    _Pragma("unroll") \
    for (int t_ = (K0)+4; t_ < NS; t_ += 4) { \
        float4 w0_ = *(const float4*)&Mp[b0_ + t_]; \
        float4 w1_ = *(const float4*)&Mp[b1_ + t_]; \
        float4 w2_ = *(const float4*)&Mp[b2_ + t_]; \
        float4 w3_ = *(const float4*)&Mp[b3_ + t_]; \
        u[t_+0] -= w0_.x*uk0_ + w1_.x*uk1_ + w2_.x*uk2_ + w3_.x*uk3_; \
        u[t_+1] -= w0_.y*uk0_ + w1_.y*uk1_ + w2_.y*uk2_ + w3_.y*uk3_; \
        u[t_+2] -= w0_.z*uk0_ + w1_.z*uk1_ + w2_.z*uk2_ + w3_.z*uk3_; \
        u[t_+3] -= w0_.w*uk0_ + w1_.w*uk1_ + w2_.w*uk2_ + w3_.w*uk3_; \
    } \
}

#define UI(K) { \
    float d0_ = tx - scs[(K)*3+0]; \
    float d1_ = ty - scs[(K)*3+1]; \
    float d2_ = tz - scs[(K)*3+2]; \
    u[(K)] = expf(-((d0_*d0_ + d1_*d1_)*ill2 + d2_*d2_*ile2)); }
#define UI10(K) UI((K)+0) UI((K)+1) UI((K)+2) UI((K)+3) UI((K)+4) \
                UI((K)+5) UI((K)+6) UI((K)+7) UI((K)+8) UI((K)+9)

// ONE main kernel, 40 blocks x 512 threads — R3 structure (344us proven)
// with ONE Jacobi change: pair indices (p,q) computed LOCALLY as integer
// math (sched_pq), prm carries only (c,s) as float2. Ledger: R3 prm-LDS
// 344 < R7 shfl 377 < R8 redundant-trans 464 — distribution via LDS
// broadcast wins; R8 died on 900 trans chains/round vs R3's 160. The one
// remaining R3 inefficiency: A2 read addresses depended on the prm float4
// -> two serialized LDS latencies per round. With local (p,q), the A2/Vts
// data reads issue CONCURRENTLY with the (c,s) prm reads -> one latency.
// Trans work stays at 160 chains/round. Op sequences identical -> bit-
// identical output.
__global__ void __launch_bounds__(NTHR, 2) gp_block(
        const float* __restrict__ sc,  const float* __restrict__ tc,
        const float* __restrict__ st,  const float* __restrict__ tsc,
        const float* __restrict__ ttc,
        const float* __restrict__ lll, const float* __restrict__ lle,
        const float* __restrict__ llt, const float* __restrict__ lnv,
        float* __restrict__ ws) {
    __shared__ __align__(16) char smem[SMEM_BYTES];
    int j = blockIdx.x, tid = threadIdx.x;

    auto A2   = (float (*)[NT][NT+1])(smem + OFF_A2);
    auto Vts  = (float (*)[44])(smem + OFF_VTS);
    auto prm  = (float2 (*)[NT/2])(smem + OFF_PRM);
    float* tcs  = (float*)(smem + OFF_TCS);
    float* gv   = (float*)(smem + OFF_GV);
    float* wtjs = (float*)(smem + OFF_WTJ);
    float* scs  = (float*)(smem + OFF_SCS);
    float* tscs = (float*)(smem + OFF_TSCS);

    float ilt2 = expf(-2.0f * llt[0]);
    if (tid < NT) tcs[tid] = tc[tid];
    for (int t = tid; t < NS*3; t += NTHR) scs[t] = sc[t];
    for (int t = tid; t < MS*3; t += NTHR) tscs[t] = tsc[t];
    __syncthreads();
    for (int idx = tid; idx < NT*NT; idx += NTHR) {
        int i = idx / NT, jj = idx - i*NT;
        float dt = tcs[i] - tcs[jj];
        float v = expf(-dt*dt*ilt2);
        if (i == jj) v += JITTER;
        A2[0][i][jj] = v;
    }
    for (int idx = tid; idx < NT*44; idx += NTHR) {
        int jr = idx / 44, k = idx - jr*44;
        Vts[jr][k] = (jr == k) ? 1.0f : 0.0f;
    }
    __syncthreads();
    int wave = tid >> 6, lane = tid & 63;
    for (int rd = 0; rd < ROUNDS; ++rd) {
        int cur = rd & 1, nxt = cur ^ 1;
        int rr = rd % (NT - 1);
        float2* wp = prm[wave];
        if (lane < NT/2) {
            // per-wave redundant (c,s) only — 160 trans chains/round total
            int p, q; sched_pq(lane, rr, p, q);
            float app = A2[cur][p][p], aqq = A2[cur][q][q], apq = A2[cur][p][q];
            float c, s;
            rot_cs(app, aqq, apq, c, s);
            wp[lane] = make_float2(c, s);
        }
        __builtin_amdgcn_wave_barrier();   // same-wave LDS in-order; pin compiler
        for (int t = tid; t < 600; t += NTHR) {
            if (t < 400) {
                int bi = t / 20, bj = t - bi*20;
                // addresses from integer math -> data reads issue with prm reads
                int pi, qi, pj, qj;
                sched_pq(bi, rr, pi, qi);
                sched_pq(bj, rr, pj, qj);
                float2 Pi = wp[bi], Pj = wp[bj];
                float a00 = A2[cur][pi][pj], a01 = A2[cur][pi][qj];
                float a10 = A2[cur][qi][pj], a11 = A2[cur][qi][qj];
                float ci = Pi.x, si = Pi.y, cj = Pj.x, sj = Pj.y;
                float b00 = ci*a00 - si*a10, b01 = ci*a01 - si*a11;
                float b10 = si*a00 + ci*a10, b11 = si*a01 + ci*a11;
                A2[nxt][pi][pj] = cj*b00 - sj*b01; A2[nxt][pi][qj] = sj*b00 + cj*b01;
                A2[nxt][qi][pj] = cj*b10 - sj*b11; A2[nxt][qi][qj] = sj*b10 + cj*b11;
            } else {
                int u2 = t - 400;
                int pr = u2 / 10, ch = (u2 - pr*10) << 2;
                int pv, qv;
                sched_pq(pr, rr, pv, qv);
                float2 P = wp[pr];
                float4 vp = *(float4*)&Vts[pv][ch];
                float4 vq = *(float4*)&Vts[qv][ch];
                float c = P.x, s = P.y;
                float4 np, nq;
                np.x = c*vp.x - s*vq.x; nq.x = s*vp.x + c*vq.x;
                np.y = c*vp.y - s*vq.y; nq.y = s*vp.y + c*vq.y;
                np.z = c*vp.z - s*vq.z; nq.z = s*vp.z + c*vq.z;
                np.w = c*vp.w - s*vq.w; nq.w = s*vp.w + c*vq.w;
                *(float4*)&Vts[pv][ch] = np;
                *(float4*)&Vts[qv][ch] = nq;
            }
        }
        __syncthreads();
    }
    const int fin = ROUNDS & 1;
    if (tid == 0) wtjs[0] = A2[fin][j][j];
    for (int s = tid; s < NS; s += NTHR) {
        const float4* va = (const float4*)&Vts[j][0];
        const float4* sa = (const float4*)&st[s*NT];
        float acc = 0.0f;
        #pragma unroll
        for (int c4 = 0; c4 < NT/4; ++c4) {
            float4 a = va[c4], b = sa[c4];
            acc += a.x*b.x + a.y*b.y + a.z*b.z + a.w*b.w;
        }
        gv[s] = acc;
    }
    if (tid < MT) {
        float ttv = ttc[tid];
        float acc = 0.0f;
        for (int t = 0; t < NT; ++t) {
            float dt = ttv - tcs[t];
            acc += expf(-dt*dt*ilt2) * Vts[j][t];
        }
        ws[WS_AW + j*32 + tid] = acc;
    }
    __syncthreads();

    // ---------- phase 2: build + rank-8 factor + scale + trsm ----------
    float* Mp   = (float*)(smem + OFF_MP);
    auto   Pr   = (float (*)[LDW])(smem + OFF_PR);
    float* invs = (float*)(smem + OFF_INVS);
    float* dvs  = (float*)(smem + OFF_DVS);
    float wtj = wtjs[0];
    float nv = expf(lnv[0]);
    float ill2 = expf(-2.0f * lll[0]);
    float ile2 = expf(-2.0f * lle[0]);
    for (int idx = tid; idx < NS*LDW; idx += NTHR) {
        int r = idx / LDW, c = idx - r*LDW;
        int rbase = r & ~3;
        if (c < rbase) continue;
        float v;
        if (c < NS) {
            float d0 = scs[r*3+0] - scs[c*3+0];
            float d1 = scs[r*3+1] - scs[c*3+1];
            float d2 = scs[r*3+2] - scs[c*3+2];
            v = wtj * expf(-((d0*d0 + d1*d1)*ill2 + d2*d2*ile2));
            if (c == r) v += wtj * JITTER + nv;   // spatial jitter rides wtj
        } else if (c == NS) {
            v = gv[r];
        } else {
            v = 0.0f;
        }
        Mp[rs_off(r) + c - rbase] = v;
    }
    __syncthreads();
    for (int k0 = 0; k0 < NS - 1; k0 += 8) {
        int P = NS - k0; if (P > 8) P = 8;
        int W4 = (LDW - k0) >> 2;
        // phase A (single wave): redundant 8x8 elimination + chunk pre-elim -> Pr
        if (tid < W4) {
            int off[8];
            #pragma unroll
            for (int i = 0; i < 8; ++i)
                off[i] = (i < P) ? (rs_off(k0 + i) - ((i >= 4) ? 4 : 0)) : 0;
            float Bm[8][8];
            #pragma unroll
            for (int i = 0; i < 8; ++i) {
                #pragma unroll
                for (int c = 0; c < 8; ++c)
                    Bm[i][c] = (i < P && c >= i) ? Mp[off[i] + c]
                                                 : ((c == i) ? 1.0f : 0.0f);
            }
            float Lf[8][8]; float iv[8];
            #pragma unroll
            for (int k = 0; k < 8; ++k) {
                iv[k] = 1.0f / Bm[k][k];
                #pragma unroll
                for (int i = k + 1; i < 8; ++i) {
                    float l = Bm[k][i] * iv[k];
                    Lf[i][k] = l;
                    #pragma unroll
                    for (int c = i; c < 8; ++c) Bm[i][c] -= l * Bm[k][c];
                }
            }
            if (tid == 0) {
                #pragma unroll
                for (int i = 0; i < 8; ++i) invs[i] = iv[i];
            }
            int C = tid << 2;
            float4 m[8];
            #pragma unroll
            for (int i = 0; i < 8; ++i) {
                bool ok = (i < P) && (i < 4 || C >= 4);
                m[i] = ok ? *(float4*)&Mp[off[i] + C] : make_float4(0,0,0,0);
            }
            #pragma unroll
            for (int i = 1; i < 8; ++i) {
                #pragma unroll
                for (int k = 0; k < i; ++k) {
                    float l = Lf[i][k];
                    m[i].x -= l*m[k].x; m[i].y -= l*m[k].y;
                    m[i].z -= l*m[k].z; m[i].w -= l*m[k].w;
                }
            }
            #pragma unroll
            for (int i = 0; i < 8; ++i) *(float4*)&Pr[i][C] = m[i];
        }
        __syncthreads();
        // phase B: rank-8 trailing update, thread-per-row, contiguous f4 sweep
        for (int r = k0 + 1 + tid; r < NS; r += NTHR) {
            int rc = r - k0;
            float f[8];
            #pragma unroll
            for (int i = 0; i < 8; ++i)
                f[i] = (rc > i && i < P) ? Pr[i][rc] * invs[i] : 0.0f;
            int rbase = r & ~3;
            int ro = rs_off(r) - rbase;
            for (int C = rbase; C < LDW; C += 4) {
                int pc = C - k0;
                float4 v = *(float4*)&Mp[ro + C];
                #pragma unroll
                for (int i = 0; i < 8; ++i) {
                    float4 p = *(float4*)&Pr[i][pc];
                    v.x -= f[i]*p.x; v.y -= f[i]*p.y;
                    v.z -= f[i]*p.z; v.w -= f[i]*p.w;
                }
                *(float4*)&Mp[ro + C] = v;
            }
        }
        __syncthreads();
    }
    // scale in place: diag slot = 1/d, cols>r (incl. RHS col 150 -> y) *= 1/d
    for (int r = tid; r < NS; r += NTHR)
        dvs[r] = rsqrtf(Mp[rs_off(r) + r - (r & ~3)]);
    __syncthreads();
    for (int idx = tid; idx < NS*LDW; idx += NTHR) {
        int r = idx / LDW, c = idx - r*LDW;
        int rbase = r & ~3;
        if (c < rbase) continue;
        int t = rs_off(r) + c - rbase;
        float dvr = dvs[r];
        if (c == r) Mp[t] = dvr;
        else if (c > r) Mp[t] *= dvr;
    }
    __syncthreads();
    // fused trsm: thread-per-test-column, u[] fully static -> register/AGPR
    if (tid < MS) {
        float tx = tscs[tid*3+0], ty = tscs[tid*3+1], tz = tscs[tid*3+2];
        float u[152];
        UI10(0)  UI10(10) UI10(20) UI10(30) UI10(40)
        UI10(50) UI10(60) UI10(70) UI10(80) UI10(90)
        UI10(100) UI10(110) UI10(120) UI10(130) UI10(140)
        u[150] = 0.0f; u[151] = 0.0f;
        float qa = 0.0f, ra = 0.0f;
        ST4(0)   ST4(4)   ST4(8)   ST4(12)  ST4(16)  ST4(20)  ST4(24)
        ST4(28)  ST4(32)  ST4(36)  ST4(40)  ST4(44)  ST4(48)  ST4(52)
        ST4(56)  ST4(60)  ST4(64)  ST4(68)  ST4(72)  ST4(76)  ST4(80)
        ST4(84)  ST4(88)  ST4(92)  ST4(96)  ST4(100) ST4(104) ST4(108)
        ST4(112) ST4(116) ST4(120) ST4(124) ST4(128) ST4(132) ST4(136)
        ST4(140) ST4(144)
        {   // tail: k = 148, 149
            constexpr int b8_ = rs_off_c(148) - 148;
            constexpr int b9_ = rs_off_c(149) - 148;
            float uk8_ = u[148] * Mp[b8_ + 148];
            qa += uk8_*uk8_;  ra += uk8_ * Mp[b8_ + 150];
            u[149] -= Mp[b8_ + 149] * uk8_;
            float uk9_ = u[149] * Mp[b9_ + 149];
            qa += uk9_*uk9_;  ra += uk9_ * Mp[b9_ + 150];
        }
        ws[WS_RV + j*256 + tid] = ra;
        ws[WS_QV + j*256 + tid] = qa;
    }
}

// ---------- reduction kernel: out = rank-40 combine of workspace partials ----------
__global__ void __launch_bounds__(256) gp_reduce(
        const float* __restrict__ ws, const float* __restrict__ lsv,
        float* __restrict__ out) {
    int idx = blockIdx.x * 256 + threadIdx.x;
    if (idx >= MS*MT) return;
    int is = idx / MT, it = idx - is*MT;
    float p = 0.0f, q = 0.0f;
    #pragma unroll
    for (int jj = 0; jj < NT; ++jj) {
        float a = ws[WS_AW + jj*32 + it];
        p += a * ws[WS_RV + jj*256 + is];
        q += a * a * ws[WS_QV + jj*256 + is];
    }
    out[idx] = p;
    out[MS*MT + idx] = expf(lsv[0]) - q;
}

extern "C" void kernel_launch(void* const* d_in, const int* in_sizes, int n_in,
                              void* d_out, int out_size, void* d_ws, size_t ws_size,
                              hipStream_t stream) {
    const float* sc  = (const float*)d_in[0];   // 150x3
    const float* tc  = (const float*)d_in[1];   // 40x1
    const float* st  = (const float*)d_in[2];   // 150x40
    const float* tsc = (const float*)d_in[3];   // 200x3
    const float* ttc = (const float*)d_in[4];   // 30x1
    const float* lll = (const float*)d_in[5];
    const float* lle = (const float*)d_in[6];
    const float* llt = (const float*)d_in[7];
    const float* lnv = (const float*)d_in[8];
    const float* lsv = (const float*)d_in[9];
    float* out = (float*)d_out;
    float* ws  = (float*)d_ws;

    hipLaunchKernelGGL(gp_block, dim3(NT), dim3(NTHR), 0, stream,
                       sc, tc, st, tsc, ttc, lll, lle, llt, lnv, ws);
    hipLaunchKernelGGL(gp_reduce, dim3((MS*MT + 255)/256), dim3(256), 0, stream,
                       ws, lsv, out);
}